// Round 1
// baseline (972.954 us; speedup 1.0000x reference)
//
#include <hip/hip_runtime.h>
#include <hip/hip_bf16.h>

// Problem constants: B=4, S=2048, D=1024, H=16, HD=64
#define S_LEN  2048
#define DMODEL 1024
#define NHEAD  16
#define HDIM   64
#define BSZ    4

typedef __bf16 bf16_t;
typedef __bf16 bf16x8 __attribute__((ext_vector_type(8)));
typedef __bf16 bf16x4 __attribute__((ext_vector_type(4)));
typedef float  f32x4  __attribute__((ext_vector_type(4)));

typedef __attribute__((address_space(1))) void as1_void;
typedef __attribute__((address_space(3))) void as3_void;

__device__ __forceinline__ f32x4 mfma16(bf16x8 a, bf16x8 b, f32x4 c) {
    return __builtin_amdgcn_mfma_f32_16x16x32_bf16(a, b, c, 0, 0, 0);
}

// ---------------------------------------------------------------------------
// Convert x (fp32) -> bf16, 4 elems/thread
__global__ __launch_bounds__(256) void cvt_x_kernel(const float* __restrict__ x,
                                                    bf16_t* __restrict__ xb, int n4) {
    int i = blockIdx.x * 256 + threadIdx.x;
    int stride = gridDim.x * 256;
    for (; i < n4; i += stride) {
        float4 v = ((const float4*)x)[i];
        bf16x4 t = { (bf16_t)v.x, (bf16_t)v.y, (bf16_t)v.z, (bf16_t)v.w };
        ((bf16x4*)xb)[i] = t;
    }
}

// Transpose 1024x1024 fp32 weight -> bf16 W^T (LDS-tiled, coalesced both sides)
__global__ __launch_bounds__(256) void cvt_wT_kernel(const float* __restrict__ w,
                                                     bf16_t* __restrict__ wT) {
    __shared__ bf16_t t[64][65];
    const int bx = blockIdx.x * 64;  // k range
    const int by = blockIdx.y * 64;  // n range
    const int tx = threadIdx.x & 63, ty = threadIdx.x >> 6;
    #pragma unroll
    for (int rr = 0; rr < 64; rr += 4) {
        // coalesced read of w[k][n], store transposed: t[n_local][k_local]
        t[tx][rr + ty] = (bf16_t)w[(size_t)(bx + rr + ty) * DMODEL + by + tx];
    }
    __syncthreads();
    #pragma unroll
    for (int rr = 0; rr < 64; rr += 4) {
        // coalesced write of wT[n][k]
        wT[(size_t)(by + rr + ty) * DMODEL + bx + tx] = t[rr + ty][tx];
    }
}

// ---------------------------------------------------------------------------
// GEMM: C = A(MxK) * Bt(NxK)^T + bias.  M=8192, N=1024, K=1024. bf16 MFMA.
// 128x128 tile, 4 waves (2x2), 16 MFMA/K-step/wave, global_load_lds width 16.
// MODE 0: write bf16 (B,H,S,HD)   (Q,K)
// MODE 1: write bf16 (B,H,HD,S)   (V transposed)
// MODE 2: write fp32 (B,S,D)      (final out-projection)
template <int MODE>
__global__ __launch_bounds__(256) void gemm_bt(const bf16_t* __restrict__ A,
                                               const bf16_t* __restrict__ Bt,
                                               const float* __restrict__ bias,
                                               void* __restrict__ outp) {
    constexpr int GK = 1024;
    __shared__ __attribute__((aligned(16))) bf16_t As[128 * 32];
    __shared__ __attribute__((aligned(16))) bf16_t Bs[128 * 32];

    const int tid  = threadIdx.x;
    const int wave = tid >> 6, lane = tid & 63;
    const int col16 = lane & 15, g = lane >> 4;
    const int wr = wave >> 1, wc = wave & 1;
    const int bn0 = blockIdx.x * 128, bm0 = blockIdx.y * 128;

    const int r4 = tid >> 2;        // 0..63 : row within a 64-row chunk
    const int c8 = (tid & 3) * 8;   // element col offset (8 bf16 = 16B)

    f32x4 acc[4][4] = {};

    for (int k0 = 0; k0 < GK; k0 += 32) {
        __syncthreads();  // protect LDS from previous iteration's readers
        #pragma unroll
        for (int i = 0; i < 2; ++i) {
            __builtin_amdgcn_global_load_lds(
                (const as1_void*)(A + (size_t)(bm0 + i * 64 + r4) * GK + k0 + c8),
                (as3_void*)(As + (i * 64 + wave * 16) * 32), 16, 0, 0);
            __builtin_amdgcn_global_load_lds(
                (const as1_void*)(Bt + (size_t)(bn0 + i * 64 + r4) * GK + k0 + c8),
                (as3_void*)(Bs + (i * 64 + wave * 16) * 32), 16, 0, 0);
        }
        __syncthreads();  // compiler drains vmcnt before barrier

        bf16x8 af[4], bfr[4];
        #pragma unroll
        for (int i = 0; i < 4; ++i) {
            af[i]  = *(const bf16x8*)(As + (wr * 64 + i * 16 + col16) * 32 + g * 8);
            bfr[i] = *(const bf16x8*)(Bs + (wc * 64 + i * 16 + col16) * 32 + g * 8);
        }
        #pragma unroll
        for (int mi = 0; mi < 4; ++mi)
            #pragma unroll
            for (int ni = 0; ni < 4; ++ni)
                acc[mi][ni] = mfma16(af[mi], bfr[ni], acc[mi][ni]);
    }

    // epilogue: D row = (lane>>4)*4 + r, col = lane&15 (m89-verified layout)
    #pragma unroll
    for (int ni = 0; ni < 4; ++ni) {
        const int gn = bn0 + wc * 64 + ni * 16 + col16;
        const float bv = bias[gn];
        #pragma unroll
        for (int mi = 0; mi < 4; ++mi) {
            #pragma unroll
            for (int r = 0; r < 4; ++r) {
                const int gm = bm0 + wr * 64 + mi * 16 + g * 4 + r;
                const float v = acc[mi][ni][r] + bv;
                if (MODE == 0) {
                    const int b = gm >> 11, s = gm & 2047, h = gn >> 6, hd = gn & 63;
                    ((bf16_t*)outp)[(((size_t)b * NHEAD + h) * S_LEN + s) * HDIM + hd] = (bf16_t)v;
                } else if (MODE == 1) {
                    const int b = gm >> 11, s = gm & 2047, h = gn >> 6, hd = gn & 63;
                    ((bf16_t*)outp)[(((size_t)b * NHEAD + h) * HDIM + hd) * S_LEN + s] = (bf16_t)v;
                } else {
                    ((float*)outp)[(size_t)gm * DMODEL + gn] = v;
                }
            }
        }
    }
}

// ---------------------------------------------------------------------------
// Pass 1: exact row max (m) and denominator (l) per (b,h,q) row.
// Block: 256 thr = 4 waves; each wave owns 64 q-rows, streams all of K.
__global__ __launch_bounds__(256) void attn_pass1(const bf16_t* __restrict__ Q,
                                                  const bf16_t* __restrict__ K,
                                                  const float* __restrict__ mask,
                                                  float* __restrict__ marr,
                                                  float* __restrict__ larr) {
    const int tid = threadIdx.x, wave = tid >> 6, lane = tid & 63;
    const int col16 = lane & 15, g = lane >> 4;
    const int bh = blockIdx.y, b = bh >> 4;
    const int q0 = blockIdx.x * 256 + wave * 64;
    const bf16_t* Qb = Q + (size_t)bh * S_LEN * HDIM;
    const bf16_t* Kb = K + (size_t)bh * S_LEN * HDIM;
    const float* mp = mask + (size_t)b * S_LEN;

    bf16x8 qa[4][2];
    #pragma unroll
    for (int mi = 0; mi < 4; ++mi)
        #pragma unroll
        for (int kh = 0; kh < 2; ++kh)
            qa[mi][kh] = *(const bf16x8*)(Qb + (size_t)(q0 + mi * 16 + col16) * HDIM + kh * 32 + g * 8);

    float mrun[4][4], lrun[4][4];
    #pragma unroll
    for (int mi = 0; mi < 4; ++mi)
        #pragma unroll
        for (int r = 0; r < 4; ++r) { mrun[mi][r] = -1e30f; lrun[mi][r] = 0.f; }

    for (int kk0 = 0; kk0 < S_LEN; kk0 += 64) {
        bf16x8 kf[4][2];
        float mv[4];
        #pragma unroll
        for (int nj = 0; nj < 4; ++nj) {
            const int kc = kk0 + nj * 16 + col16;
            kf[nj][0] = *(const bf16x8*)(Kb + (size_t)kc * HDIM + g * 8);
            kf[nj][1] = *(const bf16x8*)(Kb + (size_t)kc * HDIM + 32 + g * 8);
            mv[nj] = mp[kc] * -1e9f;
        }
        #pragma unroll
        for (int mi = 0; mi < 4; ++mi) {
            float sc[4][4];
            #pragma unroll
            for (int nj = 0; nj < 4; ++nj) {
                f32x4 a = {0.f, 0.f, 0.f, 0.f};
                a = mfma16(qa[mi][0], kf[nj][0], a);
                a = mfma16(qa[mi][1], kf[nj][1], a);
                #pragma unroll
                for (int r = 0; r < 4; ++r) sc[nj][r] = a[r] * 0.125f + mv[nj];
            }
            #pragma unroll
            for (int r = 0; r < 4; ++r) {
                float vmax = fmaxf(fmaxf(sc[0][r], sc[1][r]), fmaxf(sc[2][r], sc[3][r]));
                #pragma unroll
                for (int off = 1; off < 16; off <<= 1) vmax = fmaxf(vmax, __shfl_xor(vmax, off, 16));
                const float mnew = fmaxf(mrun[mi][r], vmax);
                float ssum = __expf(sc[0][r] - mnew) + __expf(sc[1][r] - mnew) +
                             __expf(sc[2][r] - mnew) + __expf(sc[3][r] - mnew);
                #pragma unroll
                for (int off = 1; off < 16; off <<= 1) ssum += __shfl_xor(ssum, off, 16);
                lrun[mi][r] = lrun[mi][r] * __expf(mrun[mi][r] - mnew) + ssum;
                mrun[mi][r] = mnew;
            }
        }
    }
    if (col16 == 0) {
        #pragma unroll
        for (int mi = 0; mi < 4; ++mi)
            #pragma unroll
            for (int r = 0; r < 4; ++r) {
                const int row = q0 + mi * 16 + g * 4 + r;
                marr[(size_t)bh * S_LEN + row] = mrun[mi][r];
                larr[(size_t)bh * S_LEN + row] = lrun[mi][r];
            }
    }
}

// ---------------------------------------------------------------------------
// Pass 2: recompute scores (bitwise-identical MFMA), write softmax weights
// (fp32) to d_out attn region, P->bf16 in per-wave LDS, PV MFMA, write ctx.
// Barrier-free: each wave owns its 16 q-rows and its own LDS P tile.
__global__ __launch_bounds__(256) void attn_pass2(const bf16_t* __restrict__ Q,
                                                  const bf16_t* __restrict__ K,
                                                  const bf16_t* __restrict__ Vt,
                                                  const float* __restrict__ mask,
                                                  const float* __restrict__ marr,
                                                  const float* __restrict__ larr,
                                                  float* __restrict__ attnW,
                                                  bf16_t* __restrict__ ctx) {
    __shared__ __attribute__((aligned(16))) bf16_t Pt[4][16][72];  // stride 144B: 16B-aligned, ~2-way banks
    const int tid = threadIdx.x, wave = tid >> 6, lane = tid & 63;
    const int col16 = lane & 15, g = lane >> 4;
    const int bh = blockIdx.y, b = bh >> 4, h = bh & 15;
    const int q0 = blockIdx.x * 64 + wave * 16;
    const bf16_t* Qb = Q + (size_t)bh * S_LEN * HDIM;
    const bf16_t* Kb = K + (size_t)bh * S_LEN * HDIM;
    const bf16_t* Vb = Vt + (size_t)bh * HDIM * S_LEN;
    const float* mp = mask + (size_t)b * S_LEN;

    bf16x8 qa[2];
    #pragma unroll
    for (int kh = 0; kh < 2; ++kh)
        qa[kh] = *(const bf16x8*)(Qb + (size_t)(q0 + col16) * HDIM + kh * 32 + g * 8);

    float m_r[4], il[4];
    #pragma unroll
    for (int r = 0; r < 4; ++r) {
        const int row = q0 + g * 4 + r;
        m_r[r] = marr[(size_t)bh * S_LEN + row];
        il[r]  = 1.f / larr[(size_t)bh * S_LEN + row];
    }

    f32x4 o[4] = {};

    for (int kk0 = 0; kk0 < S_LEN; kk0 += 64) {
        // --- scores + softmax weights ---
        #pragma unroll
        for (int nj = 0; nj < 4; ++nj) {
            const int kc = kk0 + nj * 16 + col16;
            bf16x8 kf0 = *(const bf16x8*)(Kb + (size_t)kc * HDIM + g * 8);
            bf16x8 kf1 = *(const bf16x8*)(Kb + (size_t)kc * HDIM + 32 + g * 8);
            const float mv = mp[kc] * -1e9f;
            f32x4 a = {0.f, 0.f, 0.f, 0.f};
            a = mfma16(qa[0], kf0, a);
            a = mfma16(qa[1], kf1, a);
            #pragma unroll
            for (int r = 0; r < 4; ++r) {
                const float p = __expf(a[r] * 0.125f + mv - m_r[r]) * il[r];
                attnW[(size_t)(bh * S_LEN + q0 + g * 4 + r) * S_LEN + kc] = p;
                Pt[wave][g * 4 + r][nj * 16 + col16] = (bf16_t)p;
            }
        }
        // --- PV (wave-local LDS; compiler inserts lgkmcnt waits) ---
        #pragma unroll
        for (int kh = 0; kh < 2; ++kh) {
            bf16x8 pa = *(const bf16x8*)(&Pt[wave][col16][kh * 32 + g * 8]);
            #pragma unroll
            for (int nd = 0; nd < 4; ++nd) {
                bf16x8 vf = *(const bf16x8*)(Vb + (size_t)(nd * 16 + col16) * S_LEN + kk0 + kh * 32 + g * 8);
                o[nd] = mfma16(pa, vf, o[nd]);
            }
        }
    }

    // ctx (B,S,D) bf16
    #pragma unroll
    for (int nd = 0; nd < 4; ++nd)
        #pragma unroll
        for (int r = 0; r < 4; ++r)
            ctx[((size_t)b * S_LEN + q0 + g * 4 + r) * DMODEL + h * HDIM + nd * 16 + col16] = (bf16_t)o[nd][r];
}

// ---------------------------------------------------------------------------
extern "C" void kernel_launch(void* const* d_in, const int* in_sizes, int n_in,
                              void* d_out, int out_size, void* d_ws, size_t ws_size,
                              hipStream_t stream) {
    const float* x    = (const float*)d_in[0];
    const float* mask = (const float*)d_in[1];
    const float* wq   = (const float*)d_in[2];
    const float* bq   = (const float*)d_in[3];
    const float* wk   = (const float*)d_in[4];
    const float* bk   = (const float*)d_in[5];
    const float* wv   = (const float*)d_in[6];
    const float* bv   = (const float*)d_in[7];
    const float* wo   = (const float*)d_in[8];
    const float* bo   = (const float*)d_in[9];

    const size_t nX = (size_t)BSZ * S_LEN * DMODEL;      // 8388608
    const size_t nW = (size_t)DMODEL * DMODEL;           // 1048576
    const size_t nR = (size_t)BSZ * NHEAD * S_LEN;       // 131072

    char* ws = (char*)d_ws;
    size_t off = 0;
    bf16_t* xb  = (bf16_t*)(ws + off); off += nX * 2;
    bf16_t* wqT = (bf16_t*)(ws + off); off += nW * 2;
    bf16_t* wkT = (bf16_t*)(ws + off); off += nW * 2;
    bf16_t* wvT = (bf16_t*)(ws + off); off += nW * 2;
    bf16_t* woT = (bf16_t*)(ws + off); off += nW * 2;
    bf16_t* qbh = (bf16_t*)(ws + off); off += nX * 2;
    bf16_t* kbh = (bf16_t*)(ws + off); off += nX * 2;
    bf16_t* vtb = (bf16_t*)(ws + off); off += nX * 2;
    bf16_t* ctx = (bf16_t*)(ws + off); off += nX * 2;
    float*  marr = (float*)(ws + off); off += nR * 4;
    float*  larr = (float*)(ws + off); off += nR * 4;
    if (ws_size < off) return;  // workspace too small: leave output zero (loud failure)

    float* outp  = (float*)d_out;
    float* attnW = outp + nX;  // out is B*S*D, then attn weights B*H*S*S

    cvt_x_kernel<<<4096, 256, 0, stream>>>(x, xb, (int)(nX / 4));
    cvt_wT_kernel<<<dim3(16, 16), 256, 0, stream>>>(wq, wqT);
    cvt_wT_kernel<<<dim3(16, 16), 256, 0, stream>>>(wk, wkT);
    cvt_wT_kernel<<<dim3(16, 16), 256, 0, stream>>>(wv, wvT);
    cvt_wT_kernel<<<dim3(16, 16), 256, 0, stream>>>(wo, woT);

    gemm_bt<0><<<dim3(8, 64), 256, 0, stream>>>(xb, wqT, bq, qbh);
    gemm_bt<0><<<dim3(8, 64), 256, 0, stream>>>(xb, wkT, bk, kbh);
    gemm_bt<1><<<dim3(8, 64), 256, 0, stream>>>(xb, wvT, bv, vtb);

    attn_pass1<<<dim3(8, 64), 256, 0, stream>>>(qbh, kbh, mask, marr, larr);
    attn_pass2<<<dim3(32, 64), 256, 0, stream>>>(qbh, kbh, vtb, mask, marr, larr, attnW, ctx);

    gemm_bt<2><<<dim3(8, 64), 256, 0, stream>>>(ctx, woT, bo, outp);
}

// Round 2
// 905.745 us; speedup vs baseline: 1.0742x; 1.0742x over previous
//
#include <hip/hip_runtime.h>
#include <hip/hip_bf16.h>

// Problem constants: B=4, S=2048, D=1024, H=16, HD=64
#define S_LEN  2048
#define DMODEL 1024
#define NHEAD  16
#define HDIM   64
#define BSZ    4

typedef __bf16 bf16_t;
typedef __bf16 bf16x8 __attribute__((ext_vector_type(8)));
typedef __bf16 bf16x4 __attribute__((ext_vector_type(4)));
typedef float  f32x4  __attribute__((ext_vector_type(4)));

typedef __attribute__((address_space(1))) void as1_void;
typedef __attribute__((address_space(3))) void as3_void;

__device__ __forceinline__ f32x4 mfma16(bf16x8 a, bf16x8 b, f32x4 c) {
    return __builtin_amdgcn_mfma_f32_16x16x32_bf16(a, b, c, 0, 0, 0);
}

// ---------------------------------------------------------------------------
// Convert x (fp32) -> bf16, 4 elems/thread
__global__ __launch_bounds__(256) void cvt_x_kernel(const float* __restrict__ x,
                                                    bf16_t* __restrict__ xb, int n4) {
    int i = blockIdx.x * 256 + threadIdx.x;
    int stride = gridDim.x * 256;
    for (; i < n4; i += stride) {
        float4 v = ((const float4*)x)[i];
        bf16x4 t = { (bf16_t)v.x, (bf16_t)v.y, (bf16_t)v.z, (bf16_t)v.w };
        ((bf16x4*)xb)[i] = t;
    }
}

// Transpose 1024x1024 fp32 weight -> bf16 W^T (LDS-tiled, coalesced both sides)
__global__ __launch_bounds__(256) void cvt_wT_kernel(const float* __restrict__ w,
                                                     bf16_t* __restrict__ wT) {
    __shared__ bf16_t t[64][65];
    const int bx = blockIdx.x * 64;  // k range
    const int by = blockIdx.y * 64;  // n range
    const int tx = threadIdx.x & 63, ty = threadIdx.x >> 6;
    #pragma unroll
    for (int rr = 0; rr < 64; rr += 4)
        t[tx][rr + ty] = (bf16_t)w[(size_t)(bx + rr + ty) * DMODEL + by + tx];
    __syncthreads();
    #pragma unroll
    for (int rr = 0; rr < 64; rr += 4)
        wT[(size_t)(by + rr + ty) * DMODEL + bx + tx] = t[rr + ty][tx];
}

// Transpose V (B,H,S,64) -> Vt (B,H,64,S), bf16, LDS 64x64 tiles.
__global__ __launch_bounds__(256) void transpose_v(const bf16_t* __restrict__ V,
                                                   bf16_t* __restrict__ Vt) {
    __shared__ __attribute__((aligned(16))) bf16_t t[64][72];
    const int bh = blockIdx.y;
    const int s0 = blockIdx.x * 64;
    const int tid = threadIdx.x;
    const bf16_t* Vb = V + (size_t)bh * S_LEN * HDIM;
    bf16_t* Vo = Vt + (size_t)bh * HDIM * S_LEN;
    #pragma unroll
    for (int p = 0; p < 2; ++p) {
        const int sl = p * 32 + (tid >> 3);
        const int c8 = (tid & 7) * 8;
        bf16x8 v = *(const bf16x8*)(Vb + (size_t)(s0 + sl) * HDIM + c8);
        #pragma unroll
        for (int j = 0; j < 8; ++j) t[c8 + j][sl] = v[j];
    }
    __syncthreads();
    #pragma unroll
    for (int p = 0; p < 2; ++p) {
        const int dl = p * 32 + (tid >> 3);
        const int s8 = (tid & 7) * 8;
        bf16x8 v = *(const bf16x8*)(&t[dl][s8]);
        *(bf16x8*)(Vo + (size_t)dl * S_LEN + s0 + s8) = v;
    }
}

// ---------------------------------------------------------------------------
// GEMM: C = A(Mx1024) * Bt(Nx1024)^T + bias. 128x128 tile, 4 waves (2x2).
// MODE 0: fused QKV (N=3072): writes Q,K,V all bf16 (B,H,S,HD) row-major.
// MODE 2: out-projection (N=1024): writes fp32 (B,S,D).
template <int MODE>
__global__ __launch_bounds__(256) void gemm_bt(const bf16_t* __restrict__ A,
                                               const bf16_t* __restrict__ Bt,
                                               const float* __restrict__ b0,
                                               const float* __restrict__ b1,
                                               const float* __restrict__ b2,
                                               bf16_t* __restrict__ o0,
                                               bf16_t* __restrict__ o1,
                                               bf16_t* __restrict__ o2,
                                               float* __restrict__ of) {
    constexpr int GK = 1024;
    __shared__ __attribute__((aligned(16))) bf16_t As[128 * 32];
    __shared__ __attribute__((aligned(16))) bf16_t Bs[128 * 32];

    const int tid  = threadIdx.x;
    const int wave = tid >> 6, lane = tid & 63;
    const int col16 = lane & 15, g = lane >> 4;
    const int wr = wave >> 1, wc = wave & 1;
    const int bn0 = blockIdx.x * 128, bm0 = blockIdx.y * 128;

    const int r4 = tid >> 2;
    const int c8 = (tid & 3) * 8;

    f32x4 acc[4][4] = {};

    for (int k0 = 0; k0 < GK; k0 += 32) {
        __syncthreads();
        #pragma unroll
        for (int i = 0; i < 2; ++i) {
            __builtin_amdgcn_global_load_lds(
                (const as1_void*)(A + (size_t)(bm0 + i * 64 + r4) * GK + k0 + c8),
                (as3_void*)(As + (i * 64 + wave * 16) * 32), 16, 0, 0);
            __builtin_amdgcn_global_load_lds(
                (const as1_void*)(Bt + (size_t)(bn0 + i * 64 + r4) * GK + k0 + c8),
                (as3_void*)(Bs + (i * 64 + wave * 16) * 32), 16, 0, 0);
        }
        __syncthreads();

        bf16x8 af[4], bfr[4];
        #pragma unroll
        for (int i = 0; i < 4; ++i) {
            af[i]  = *(const bf16x8*)(As + (wr * 64 + i * 16 + col16) * 32 + g * 8);
            bfr[i] = *(const bf16x8*)(Bs + (wc * 64 + i * 16 + col16) * 32 + g * 8);
        }
        #pragma unroll
        for (int mi = 0; mi < 4; ++mi)
            #pragma unroll
            for (int ni = 0; ni < 4; ++ni)
                acc[mi][ni] = mfma16(af[mi], bfr[ni], acc[mi][ni]);
    }

    #pragma unroll
    for (int ni = 0; ni < 4; ++ni) {
        const int gn = bn0 + wc * 64 + ni * 16 + col16;
        if (MODE == 0) {
            const int proj = bn0 >> 10;                 // uniform per block
            const float* bias = proj == 0 ? b0 : (proj == 1 ? b1 : b2);
            bf16_t* outp      = proj == 0 ? o0 : (proj == 1 ? o1 : o2);
            const int n1 = gn & 1023, h = n1 >> 6, hd = n1 & 63;
            const float bv = bias[n1];
            #pragma unroll
            for (int mi = 0; mi < 4; ++mi)
                #pragma unroll
                for (int r = 0; r < 4; ++r) {
                    const int gm = bm0 + wr * 64 + mi * 16 + g * 4 + r;
                    const int b = gm >> 11, s = gm & 2047;
                    outp[(((size_t)b * NHEAD + h) * S_LEN + s) * HDIM + hd] =
                        (bf16_t)(acc[mi][ni][r] + bv);
                }
        } else {
            const float bv = b0[gn];
            #pragma unroll
            for (int mi = 0; mi < 4; ++mi)
                #pragma unroll
                for (int r = 0; r < 4; ++r) {
                    const int gm = bm0 + wr * 64 + mi * 16 + g * 4 + r;
                    of[(size_t)gm * DMODEL + gn] = acc[mi][ni][r] + bv;
                }
        }
    }
}

// ---------------------------------------------------------------------------
// Fused attention: swapped-operand QK^T (scores lane-local), two sweeps.
// Sweep 1: exact per-row max m + denominator l (per-lane online, 2 shfl at end).
// Sweep 2: identical score bits -> p = exp(s-m)/l; float4 nt store to attnW;
//          P->bf16 via wave-private LDS -> PV MFMA (O^T = V^T * P^T).
// Each wave owns 16 q-rows; no barriers.
__global__ __launch_bounds__(256) void attn_fused(const bf16_t* __restrict__ Q,
                                                  const bf16_t* __restrict__ K,
                                                  const bf16_t* __restrict__ Vt,
                                                  const float* __restrict__ mask,
                                                  float* __restrict__ attnW,
                                                  bf16_t* __restrict__ ctx) {
    __shared__ __attribute__((aligned(16))) bf16_t Pt[4][16][72];
    const int tid = threadIdx.x, wave = tid >> 6, lane = tid & 63;
    const int col16 = lane & 15, g = lane >> 4;
    const int bh = blockIdx.y, b = bh >> 4, h = bh & 15;
    const int q0 = blockIdx.x * 64 + wave * 16;
    const bf16_t* Qb = Q + (size_t)bh * S_LEN * HDIM;
    const bf16_t* Kb = K + (size_t)bh * S_LEN * HDIM;
    const bf16_t* Vb = Vt + (size_t)bh * HDIM * S_LEN;
    const float* mp = mask + (size_t)b * S_LEN;

    // Q B-frag: col=q=col16, k-dim=hd=g*8+j
    const bf16x8 qa0 = *(const bf16x8*)(Qb + (size_t)(q0 + col16) * HDIM + g * 8);
    const bf16x8 qa1 = *(const bf16x8*)(Qb + (size_t)(q0 + col16) * HDIM + 32 + g * 8);

    // ---- sweep 1: per-lane online max/denominator ----
    float mrun = -1e30f, lrun = 0.f;
    for (int kk0 = 0; kk0 < S_LEN; kk0 += 64) {
        f32x4 sc[4];
        #pragma unroll
        for (int nj = 0; nj < 4; ++nj) {
            const bf16_t* kp = Kb + (size_t)(kk0 + nj * 16 + col16) * HDIM;
            f32x4 a = {0.f, 0.f, 0.f, 0.f};
            a = mfma16(*(const bf16x8*)(kp + g * 8), qa0, a);
            a = mfma16(*(const bf16x8*)(kp + 32 + g * 8), qa1, a);
            const f32x4 mv = ((const f32x4*)(mp + kk0 + nj * 16))[g];
            #pragma unroll
            for (int r = 0; r < 4; ++r) sc[nj][r] = fmaf(a[r], 0.125f, mv[r] * -1e9f);
        }
        f32x4 mx = sc[0];
        #pragma unroll
        for (int nj = 1; nj < 4; ++nj)
            #pragma unroll
            for (int r = 0; r < 4; ++r) mx[r] = fmaxf(mx[r], sc[nj][r]);
        const float pmax = fmaxf(fmaxf(mx[0], mx[1]), fmaxf(mx[2], mx[3]));
        const float mnew = fmaxf(mrun, pmax);
        f32x4 sv = {0.f, 0.f, 0.f, 0.f};
        #pragma unroll
        for (int nj = 0; nj < 4; ++nj)
            #pragma unroll
            for (int r = 0; r < 4; ++r) sv[r] += __expf(sc[nj][r] - mnew);
        lrun = fmaf(lrun, __expf(mrun - mnew), (sv[0] + sv[1]) + (sv[2] + sv[3]));
        mrun = mnew;
    }
    // merge the 4 g-groups (lanes L, L^16, L^32, L^48 hold disjoint k-slices of q=col16)
    #pragma unroll
    for (int xm = 16; xm <= 32; xm <<= 1) {
        const float mo = __shfl_xor(mrun, xm);
        const float lo = __shfl_xor(lrun, xm);
        const float mn = fmaxf(mrun, mo);
        lrun = lrun * __expf(mrun - mn) + lo * __expf(mo - mn);
        mrun = mn;
    }
    const float m_fin = mrun;
    const float il = 1.f / lrun;

    // ---- sweep 2: normalized weights + PV ----
    f32x4 o[4] = {};
    float* aw = attnW + (size_t)(bh * S_LEN + q0 + col16) * S_LEN;
    for (int kk0 = 0; kk0 < S_LEN; kk0 += 64) {
        #pragma unroll
        for (int nj = 0; nj < 4; ++nj) {
            const bf16_t* kp = Kb + (size_t)(kk0 + nj * 16 + col16) * HDIM;
            f32x4 a = {0.f, 0.f, 0.f, 0.f};
            a = mfma16(*(const bf16x8*)(kp + g * 8), qa0, a);
            a = mfma16(*(const bf16x8*)(kp + 32 + g * 8), qa1, a);
            const f32x4 mv = ((const f32x4*)(mp + kk0 + nj * 16))[g];
            f32x4 pn;
            bf16x4 pb;
            #pragma unroll
            for (int r = 0; r < 4; ++r) {
                const float s = fmaf(a[r], 0.125f, mv[r] * -1e9f);  // same bits as sweep 1
                pn[r] = __expf(s - m_fin) * il;
                pb[r] = (bf16_t)pn[r];
            }
            __builtin_nontemporal_store(pn, (f32x4*)(aw + kk0 + nj * 16 + g * 4));
            *(bf16x4*)(&Pt[wave][col16][nj * 16 + g * 4]) = pb;  // ds_write_b64
        }
        // PV: O^T = V^T * P^T.  A=V^T frag (row=d, k=s), B=P^T frag (col=q, k=s)
        #pragma unroll
        for (int kh = 0; kh < 2; ++kh) {
            const bf16x8 pa = *(const bf16x8*)(&Pt[wave][col16][kh * 32 + g * 8]);
            #pragma unroll
            for (int nd = 0; nd < 4; ++nd) {
                const bf16x8 vf = *(const bf16x8*)(Vb + (size_t)(nd * 16 + col16) * S_LEN +
                                                   kk0 + kh * 32 + g * 8);
                o[nd] = mfma16(vf, pa, o[nd]);
            }
        }
    }

    // ctx (B,S,D) bf16: lane holds d = nd*16 + g*4 + r for q = q0+col16 -> b64 stores
    bf16_t* cp = ctx + ((size_t)b * S_LEN + q0 + col16) * DMODEL + h * HDIM;
    #pragma unroll
    for (int nd = 0; nd < 4; ++nd) {
        bf16x4 cv;
        #pragma unroll
        for (int r = 0; r < 4; ++r) cv[r] = (bf16_t)o[nd][r];
        *(bf16x4*)(cp + nd * 16 + g * 4) = cv;
    }
}

// ---------------------------------------------------------------------------
extern "C" void kernel_launch(void* const* d_in, const int* in_sizes, int n_in,
                              void* d_out, int out_size, void* d_ws, size_t ws_size,
                              hipStream_t stream) {
    const float* x    = (const float*)d_in[0];
    const float* mask = (const float*)d_in[1];
    const float* wq   = (const float*)d_in[2];
    const float* bq   = (const float*)d_in[3];
    const float* wk   = (const float*)d_in[4];
    const float* bk   = (const float*)d_in[5];
    const float* wv   = (const float*)d_in[6];
    const float* bv   = (const float*)d_in[7];
    const float* wo   = (const float*)d_in[8];
    const float* bo   = (const float*)d_in[9];

    const size_t nX = (size_t)BSZ * S_LEN * DMODEL;      // 8388608
    const size_t nW = (size_t)DMODEL * DMODEL;           // 1048576

    char* ws = (char*)d_ws;
    size_t off = 0;
    bf16_t* xb     = (bf16_t*)(ws + off); off += nX * 2;
    bf16_t* wqkvT  = (bf16_t*)(ws + off); off += 3 * nW * 2;
    bf16_t* woT    = (bf16_t*)(ws + off); off += nW * 2;
    bf16_t* qbh    = (bf16_t*)(ws + off); off += nX * 2;
    bf16_t* kbh    = (bf16_t*)(ws + off); off += nX * 2;
    bf16_t* vrow   = (bf16_t*)(ws + off); off += nX * 2;
    bf16_t* vtb    = (bf16_t*)(ws + off); off += nX * 2;
    bf16_t* ctx    = (bf16_t*)(ws + off); off += nX * 2;
    if (ws_size < off) return;  // workspace too small: loud failure (output stays zero)

    float* outp  = (float*)d_out;
    float* attnW = outp + nX;  // out is B*S*D, then attn weights B*H*S*S

    cvt_x_kernel<<<4096, 256, 0, stream>>>(x, xb, (int)(nX / 4));
    cvt_wT_kernel<<<dim3(16, 16), 256, 0, stream>>>(wq, wqkvT);
    cvt_wT_kernel<<<dim3(16, 16), 256, 0, stream>>>(wk, wqkvT + nW);
    cvt_wT_kernel<<<dim3(16, 16), 256, 0, stream>>>(wv, wqkvT + 2 * nW);
    cvt_wT_kernel<<<dim3(16, 16), 256, 0, stream>>>(wo, woT);

    gemm_bt<0><<<dim3(24, 64), 256, 0, stream>>>(xb, wqkvT, bq, bk, bv,
                                                 qbh, kbh, vrow, nullptr);
    transpose_v<<<dim3(32, 64), 256, 0, stream>>>(vrow, vtb);

    attn_fused<<<dim3(32, 64), 256, 0, stream>>>(qbh, kbh, vtb, mask, attnW, ctx);

    gemm_bt<2><<<dim3(8, 64), 256, 0, stream>>>(ctx, woT, bo, nullptr, nullptr,
                                                nullptr, nullptr, nullptr, outp);
}

// Round 3
// 528.509 us; speedup vs baseline: 1.8409x; 1.7138x over previous
//
#include <hip/hip_runtime.h>
#include <hip/hip_bf16.h>

// Problem constants: B=4, S=2048, D=1024, H=16, HD=64
#define S_LEN  2048
#define DMODEL 1024
#define NHEAD  16
#define HDIM   64
#define BSZ    4

typedef __bf16 bf16_t;
typedef __bf16 bf16x8 __attribute__((ext_vector_type(8)));
typedef __bf16 bf16x4 __attribute__((ext_vector_type(4)));
typedef float  f32x4  __attribute__((ext_vector_type(4)));

typedef __attribute__((address_space(1))) void as1_void;
typedef __attribute__((address_space(3))) void as3_void;

__device__ __forceinline__ f32x4 mfma16(bf16x8 a, bf16x8 b, f32x4 c) {
    return __builtin_amdgcn_mfma_f32_16x16x32_bf16(a, b, c, 0, 0, 0);
}

// ---------------------------------------------------------------------------
__global__ __launch_bounds__(256) void cvt_x_kernel(const float* __restrict__ x,
                                                    bf16_t* __restrict__ xb, int n4) {
    int i = blockIdx.x * 256 + threadIdx.x;
    int stride = gridDim.x * 256;
    for (; i < n4; i += stride) {
        float4 v = ((const float4*)x)[i];
        bf16x4 t = { (bf16_t)v.x, (bf16_t)v.y, (bf16_t)v.z, (bf16_t)v.w };
        ((bf16x4*)xb)[i] = t;
    }
}

__global__ __launch_bounds__(256) void cvt_wT_kernel(const float* __restrict__ w,
                                                     bf16_t* __restrict__ wT) {
    __shared__ bf16_t t[64][65];
    const int bx = blockIdx.x * 64;
    const int by = blockIdx.y * 64;
    const int tx = threadIdx.x & 63, ty = threadIdx.x >> 6;
    #pragma unroll
    for (int rr = 0; rr < 64; rr += 4)
        t[tx][rr + ty] = (bf16_t)w[(size_t)(bx + rr + ty) * DMODEL + by + tx];
    __syncthreads();
    #pragma unroll
    for (int rr = 0; rr < 64; rr += 4)
        wT[(size_t)(by + rr + ty) * DMODEL + bx + tx] = t[rr + ty][tx];
}

__global__ __launch_bounds__(256) void transpose_v(const bf16_t* __restrict__ V,
                                                   bf16_t* __restrict__ Vt) {
    __shared__ __attribute__((aligned(16))) bf16_t t[64][72];
    const int bh = blockIdx.y;
    const int s0 = blockIdx.x * 64;
    const int tid = threadIdx.x;
    const bf16_t* Vb = V + (size_t)bh * S_LEN * HDIM;
    bf16_t* Vo = Vt + (size_t)bh * HDIM * S_LEN;
    #pragma unroll
    for (int p = 0; p < 2; ++p) {
        const int sl = p * 32 + (tid >> 3);
        const int c8 = (tid & 7) * 8;
        bf16x8 v = *(const bf16x8*)(Vb + (size_t)(s0 + sl) * HDIM + c8);
        #pragma unroll
        for (int j = 0; j < 8; ++j) t[c8 + j][sl] = v[j];
    }
    __syncthreads();
    #pragma unroll
    for (int p = 0; p < 2; ++p) {
        const int dl = p * 32 + (tid >> 3);
        const int s8 = (tid & 7) * 8;
        bf16x8 v = *(const bf16x8*)(&t[dl][s8]);
        *(bf16x8*)(Vo + (size_t)dl * S_LEN + s0 + s8) = v;
    }
}

// ---------------------------------------------------------------------------
// GEMM: C = A(Mx1024) * Bt(Nx1024)^T + bias. 128x128 tile, 4 waves (2x2).
// MODE 0: fused QKV (N=3072): Q,K,V bf16 (B,H,S,HD) row-major.
// MODE 2: out-projection (N=1024): fp32 (B,S,D).
template <int MODE>
__global__ __launch_bounds__(256) void gemm_bt(const bf16_t* __restrict__ A,
                                               const bf16_t* __restrict__ Bt,
                                               const float* __restrict__ b0,
                                               const float* __restrict__ b1,
                                               const float* __restrict__ b2,
                                               bf16_t* __restrict__ o0,
                                               bf16_t* __restrict__ o1,
                                               bf16_t* __restrict__ o2,
                                               float* __restrict__ of) {
    constexpr int GK = 1024;
    __shared__ __attribute__((aligned(16))) bf16_t As[128 * 32];
    __shared__ __attribute__((aligned(16))) bf16_t Bs[128 * 32];

    const int tid  = threadIdx.x;
    const int wave = tid >> 6, lane = tid & 63;
    const int col16 = lane & 15, g = lane >> 4;
    const int wr = wave >> 1, wc = wave & 1;
    const int bn0 = blockIdx.x * 128, bm0 = blockIdx.y * 128;

    const int r4 = tid >> 2;
    const int c8 = (tid & 3) * 8;

    f32x4 acc[4][4] = {};

    for (int k0 = 0; k0 < GK; k0 += 32) {
        __syncthreads();
        #pragma unroll
        for (int i = 0; i < 2; ++i) {
            __builtin_amdgcn_global_load_lds(
                (const as1_void*)(A + (size_t)(bm0 + i * 64 + r4) * GK + k0 + c8),
                (as3_void*)(As + (i * 64 + wave * 16) * 32), 16, 0, 0);
            __builtin_amdgcn_global_load_lds(
                (const as1_void*)(Bt + (size_t)(bn0 + i * 64 + r4) * GK + k0 + c8),
                (as3_void*)(Bs + (i * 64 + wave * 16) * 32), 16, 0, 0);
        }
        __syncthreads();

        bf16x8 af[4], bfr[4];
        #pragma unroll
        for (int i = 0; i < 4; ++i) {
            af[i]  = *(const bf16x8*)(As + (wr * 64 + i * 16 + col16) * 32 + g * 8);
            bfr[i] = *(const bf16x8*)(Bs + (wc * 64 + i * 16 + col16) * 32 + g * 8);
        }
        #pragma unroll
        for (int mi = 0; mi < 4; ++mi)
            #pragma unroll
            for (int ni = 0; ni < 4; ++ni)
                acc[mi][ni] = mfma16(af[mi], bfr[ni], acc[mi][ni]);
    }

    #pragma unroll
    for (int ni = 0; ni < 4; ++ni) {
        const int gn = bn0 + wc * 64 + ni * 16 + col16;
        if (MODE == 0) {
            const int proj = bn0 >> 10;
            const float* bias = proj == 0 ? b0 : (proj == 1 ? b1 : b2);
            bf16_t* outp      = proj == 0 ? o0 : (proj == 1 ? o1 : o2);
            const int n1 = gn & 1023, h = n1 >> 6, hd = n1 & 63;
            const float bv = bias[n1];
            #pragma unroll
            for (int mi = 0; mi < 4; ++mi)
                #pragma unroll
                for (int r = 0; r < 4; ++r) {
                    const int gm = bm0 + wr * 64 + mi * 16 + g * 4 + r;
                    const int b = gm >> 11, s = gm & 2047;
                    outp[(((size_t)b * NHEAD + h) * S_LEN + s) * HDIM + hd] =
                        (bf16_t)(acc[mi][ni][r] + bv);
                }
        } else {
            const float bv = b0[gn];
            #pragma unroll
            for (int mi = 0; mi < 4; ++mi)
                #pragma unroll
                for (int r = 0; r < 4; ++r) {
                    const int gm = bm0 + wr * 64 + mi * 16 + g * 4 + r;
                    of[(size_t)gm * DMODEL + gn] = acc[mi][ni][r] + bv;
                }
        }
    }
}

// ---------------------------------------------------------------------------
// Fused attention v3.
// 4 waves/block, wave owns 32 q-rows (2 halves of 16), QK^T swapped-operand so
// scores are lane-local. K explicitly double-buffered in registers (named
// buffers, manual 2x unroll). launch_bounds(256,2) gives the compiler ~256
// VGPRs so loads stay in flight instead of serializing on vmcnt.
// XCD-chunked swizzle: all 16 q-tiles of a head share one XCD's L2.
__global__ __launch_bounds__(256, 2) void attn_fused(const bf16_t* __restrict__ Q,
                                                     const bf16_t* __restrict__ K,
                                                     const bf16_t* __restrict__ Vt,
                                                     const float* __restrict__ mask,
                                                     float* __restrict__ attnW,
                                                     bf16_t* __restrict__ ctx) {
    __shared__ __attribute__((aligned(16))) bf16_t Pt[4][32][72];
    const int tid = threadIdx.x, wave = tid >> 6, lane = tid & 63;
    const int col16 = lane & 15, g = lane >> 4;

    // bijective XCD swizzle (1024 blocks, 1024 % 8 == 0)
    const int lin = blockIdx.y * 16 + blockIdx.x;
    const int logical = (lin & 7) * 128 + (lin >> 3);
    const int bh = logical >> 4, qt = logical & 15;
    const int b = bh >> 4, h = bh & 15;
    const int q0 = qt * 128 + wave * 32;

    const bf16_t* Qb = Q + (size_t)bh * S_LEN * HDIM;
    const bf16_t* Kb = K + (size_t)bh * S_LEN * HDIM;
    const bf16_t* Vb = Vt + (size_t)bh * HDIM * S_LEN;
    const float* mp = mask + (size_t)b * S_LEN;

    // Q B-frags for both 16-row halves
    bf16x8 qa[2][2];
    #pragma unroll
    for (int hh = 0; hh < 2; ++hh)
        #pragma unroll
        for (int kh = 0; kh < 2; ++kh)
            qa[hh][kh] = *(const bf16x8*)(Qb + (size_t)(q0 + hh * 16 + col16) * HDIM +
                                          kh * 32 + g * 8);

    bf16x8 kbA[8], kbB[8];
    auto loadK = [&](bf16x8 (&dst)[8], int it) {
        const int kk0 = it << 6;
        #pragma unroll
        for (int nj = 0; nj < 4; ++nj) {
            const bf16_t* kp = Kb + (size_t)(kk0 + nj * 16 + col16) * HDIM + g * 8;
            dst[nj * 2]     = *(const bf16x8*)(kp);
            dst[nj * 2 + 1] = *(const bf16x8*)(kp + 32);
        }
    };

    // ---- sweep 1: exact online max + denominator (lane-local) ----
    float mrun[2] = {-1e30f, -1e30f}, lrun[2] = {0.f, 0.f};

    auto body1 = [&](bf16x8 (&kc)[8], bf16x8 (&kn)[8], int it) {
        const int kk0 = it << 6;
        if (it < 31) loadK(kn, it + 1);
        f32x4 mv[4];
        #pragma unroll
        for (int nj = 0; nj < 4; ++nj) mv[nj] = ((const f32x4*)(mp + kk0 + nj * 16))[g];
        f32x4 sc[2][4];
        __builtin_amdgcn_s_setprio(1);
        #pragma unroll
        for (int nj = 0; nj < 4; ++nj) {
            f32x4 t0 = {0.f, 0.f, 0.f, 0.f}, t1 = {0.f, 0.f, 0.f, 0.f};
            t0 = mfma16(kc[nj * 2], qa[0][0], t0);
            t0 = mfma16(kc[nj * 2 + 1], qa[0][1], t0);
            t1 = mfma16(kc[nj * 2], qa[1][0], t1);
            t1 = mfma16(kc[nj * 2 + 1], qa[1][1], t1);
            sc[0][nj] = t0;
            sc[1][nj] = t1;
        }
        __builtin_amdgcn_s_setprio(0);
        #pragma unroll
        for (int hh = 0; hh < 2; ++hh) {
            #pragma unroll
            for (int nj = 0; nj < 4; ++nj)
                #pragma unroll
                for (int r = 0; r < 4; ++r)
                    sc[hh][nj][r] = fmaf(sc[hh][nj][r], 0.125f, mv[nj][r] * -1e9f);
            f32x4 mx = sc[hh][0];
            #pragma unroll
            for (int nj = 1; nj < 4; ++nj)
                #pragma unroll
                for (int r = 0; r < 4; ++r) mx[r] = fmaxf(mx[r], sc[hh][nj][r]);
            const float pmax = fmaxf(fmaxf(mx[0], mx[1]), fmaxf(mx[2], mx[3]));
            const float mnew = fmaxf(mrun[hh], pmax);
            float sv = 0.f;
            #pragma unroll
            for (int nj = 0; nj < 4; ++nj)
                #pragma unroll
                for (int r = 0; r < 4; ++r) sv += __expf(sc[hh][nj][r] - mnew);
            lrun[hh] = fmaf(lrun[hh], __expf(mrun[hh] - mnew), sv);
            mrun[hh] = mnew;
        }
    };

    loadK(kbA, 0);
    for (int it = 0; it < 32; it += 2) {
        body1(kbA, kbB, it);
        body1(kbB, kbA, it + 1);
    }

    float m_fin[2], il[2];
    #pragma unroll
    for (int hh = 0; hh < 2; ++hh) {
        float mr = mrun[hh], lr = lrun[hh];
        #pragma unroll
        for (int xm = 16; xm <= 32; xm <<= 1) {
            const float mo = __shfl_xor(mr, xm);
            const float lo = __shfl_xor(lr, xm);
            const float mn = fmaxf(mr, mo);
            lr = lr * __expf(mr - mn) + lo * __expf(mo - mn);
            mr = mn;
        }
        m_fin[hh] = mr;
        il[hh] = 1.f / lr;
    }

    // ---- sweep 2: normalized weights (identical score bits) + PV ----
    f32x4 o[2][4] = {};
    float* awp[2];
    #pragma unroll
    for (int hh = 0; hh < 2; ++hh)
        awp[hh] = attnW + (size_t)(bh * S_LEN + q0 + hh * 16 + col16) * S_LEN;

    auto body2 = [&](bf16x8 (&kc)[8], bf16x8 (&kn)[8], int it) {
        const int kk0 = it << 6;
        if (it < 31) loadK(kn, it + 1);
        bf16x8 vb[8];
        #pragma unroll
        for (int nd = 0; nd < 4; ++nd) {
            const bf16_t* vp = Vb + (size_t)(nd * 16 + col16) * S_LEN + kk0 + g * 8;
            vb[nd * 2]     = *(const bf16x8*)(vp);
            vb[nd * 2 + 1] = *(const bf16x8*)(vp + 32);
        }
        f32x4 mv[4];
        #pragma unroll
        for (int nj = 0; nj < 4; ++nj) mv[nj] = ((const f32x4*)(mp + kk0 + nj * 16))[g];

        f32x4 a[2][4];
        __builtin_amdgcn_s_setprio(1);
        #pragma unroll
        for (int nj = 0; nj < 4; ++nj) {
            f32x4 t0 = {0.f, 0.f, 0.f, 0.f}, t1 = {0.f, 0.f, 0.f, 0.f};
            t0 = mfma16(kc[nj * 2], qa[0][0], t0);
            t0 = mfma16(kc[nj * 2 + 1], qa[0][1], t0);
            t1 = mfma16(kc[nj * 2], qa[1][0], t1);
            t1 = mfma16(kc[nj * 2 + 1], qa[1][1], t1);
            a[0][nj] = t0;
            a[1][nj] = t1;
        }
        __builtin_amdgcn_s_setprio(0);
        #pragma unroll
        for (int hh = 0; hh < 2; ++hh)
            #pragma unroll
            for (int nj = 0; nj < 4; ++nj) {
                f32x4 pn;
                bf16x4 pb;
                #pragma unroll
                for (int r = 0; r < 4; ++r) {
                    const float s = fmaf(a[hh][nj][r], 0.125f, mv[nj][r] * -1e9f);
                    pn[r] = __expf(s - m_fin[hh]) * il[hh];
                    pb[r] = (bf16_t)pn[r];
                }
                __builtin_nontemporal_store(pn, (f32x4*)(awp[hh] + kk0 + nj * 16 + g * 4));
                *(bf16x4*)(&Pt[wave][hh * 16 + col16][nj * 16 + g * 4]) = pb;
            }
        __builtin_amdgcn_s_setprio(1);
        #pragma unroll
        for (int hh = 0; hh < 2; ++hh)
            #pragma unroll
            for (int kh = 0; kh < 2; ++kh) {
                const bf16x8 pa = *(const bf16x8*)(&Pt[wave][hh * 16 + col16][kh * 32 + g * 8]);
                #pragma unroll
                for (int nd = 0; nd < 4; ++nd)
                    o[hh][nd] = mfma16(vb[nd * 2 + kh], pa, o[hh][nd]);
            }
        __builtin_amdgcn_s_setprio(0);
    };

    loadK(kbA, 0);
    for (int it = 0; it < 32; it += 2) {
        body2(kbA, kbB, it);
        body2(kbB, kbA, it + 1);
    }

    // ctx (B,S,D) bf16
    #pragma unroll
    for (int hh = 0; hh < 2; ++hh) {
        bf16_t* cp = ctx + ((size_t)b * S_LEN + q0 + hh * 16 + col16) * DMODEL + h * HDIM;
        #pragma unroll
        for (int nd = 0; nd < 4; ++nd) {
            bf16x4 cv;
            #pragma unroll
            for (int r = 0; r < 4; ++r) cv[r] = (bf16_t)o[hh][nd][r];
            *(bf16x4*)(cp + nd * 16 + g * 4) = cv;
        }
    }
}

// ---------------------------------------------------------------------------
extern "C" void kernel_launch(void* const* d_in, const int* in_sizes, int n_in,
                              void* d_out, int out_size, void* d_ws, size_t ws_size,
                              hipStream_t stream) {
    const float* x    = (const float*)d_in[0];
    const float* mask = (const float*)d_in[1];
    const float* wq   = (const float*)d_in[2];
    const float* bq   = (const float*)d_in[3];
    const float* wk   = (const float*)d_in[4];
    const float* bk   = (const float*)d_in[5];
    const float* wv   = (const float*)d_in[6];
    const float* bv   = (const float*)d_in[7];
    const float* wo   = (const float*)d_in[8];
    const float* bo   = (const float*)d_in[9];

    const size_t nX = (size_t)BSZ * S_LEN * DMODEL;      // 8388608
    const size_t nW = (size_t)DMODEL * DMODEL;           // 1048576

    char* ws = (char*)d_ws;
    size_t off = 0;
    bf16_t* xb     = (bf16_t*)(ws + off); off += nX * 2;
    bf16_t* wqkvT  = (bf16_t*)(ws + off); off += 3 * nW * 2;
    bf16_t* woT    = (bf16_t*)(ws + off); off += nW * 2;
    bf16_t* qbh    = (bf16_t*)(ws + off); off += nX * 2;
    bf16_t* kbh    = (bf16_t*)(ws + off); off += nX * 2;
    bf16_t* vrow   = (bf16_t*)(ws + off); off += nX * 2;
    bf16_t* vtb    = (bf16_t*)(ws + off); off += nX * 2;
    bf16_t* ctx    = (bf16_t*)(ws + off); off += nX * 2;
    if (ws_size < off) return;  // workspace too small: loud failure (output stays zero)

    float* outp  = (float*)d_out;
    float* attnW = outp + nX;  // out is B*S*D, then attn weights B*H*S*S

    cvt_x_kernel<<<4096, 256, 0, stream>>>(x, xb, (int)(nX / 4));
    cvt_wT_kernel<<<dim3(16, 16), 256, 0, stream>>>(wq, wqkvT);
    cvt_wT_kernel<<<dim3(16, 16), 256, 0, stream>>>(wk, wqkvT + nW);
    cvt_wT_kernel<<<dim3(16, 16), 256, 0, stream>>>(wv, wqkvT + 2 * nW);
    cvt_wT_kernel<<<dim3(16, 16), 256, 0, stream>>>(wo, woT);

    gemm_bt<0><<<dim3(24, 64), 256, 0, stream>>>(xb, wqkvT, bq, bk, bv,
                                                 qbh, kbh, vrow, nullptr);
    transpose_v<<<dim3(32, 64), 256, 0, stream>>>(vrow, vtb);

    attn_fused<<<dim3(16, 64), 256, 0, stream>>>(qbh, kbh, vtb, mask, attnW, ctx);

    gemm_bt<2><<<dim3(8, 64), 256, 0, stream>>>(ctx, woT, bo, nullptr, nullptr,
                                                nullptr, nullptr, nullptr, outp);
}